// Round 1
// 1546.704 us; speedup vs baseline: 1.0125x; 1.0125x over previous
//
#include <hip/hip_runtime.h>
#include <math.h>

typedef unsigned int uint;
typedef unsigned short u16;
typedef __bf16 v8bf __attribute__((ext_vector_type(8)));
typedef float v4f __attribute__((ext_vector_type(4)));

#define GLP(x) ((const __attribute__((address_space(1))) void*)(x))
#define LDP(x) ((__attribute__((address_space(3))) void*)(x))

__device__ inline u16 f2b(float f) {
  union { float f; uint u; } c; c.f = f;
  uint u = c.u;
  return (u16)((u + 0x7fffu + ((u >> 16) & 1u)) >> 16);
}

// ---------------- embed: x = tok_emb[idx] + pos_emb, also bf16 copy ----------
__global__ __launch_bounds__(256) void k_embed(
    const int* __restrict__ idx, const float* __restrict__ tok,
    const float* __restrict__ pos, float* __restrict__ x,
    u16* __restrict__ xb, int T, int D) {
  const int r = blockIdx.x;
  const int t = threadIdx.x;             // 256 threads * float4 = 1024 = D
  const int token = idx[r];
  const int p = r % T;
  const float4 a = ((const float4*)(tok + (size_t)token * D))[t];
  const float4 b = ((const float4*)(pos + (size_t)p * D))[t];
  float4 o;
  o.x = a.x + b.x; o.y = a.y + b.y; o.z = a.z + b.z; o.w = a.w + b.w;
  ((float4*)(x + (size_t)r * D))[t] = o;
  ushort4 ob;
  ob.x = f2b(o.x); ob.y = f2b(o.y); ob.z = f2b(o.z); ob.w = f2b(o.w);
  ((ushort4*)(xb + (size_t)r * D))[t] = ob;
}

// ---------------- transpose + cast f32[R,C] -> bf16[C,R] ----------------
__global__ __launch_bounds__(256) void k_castT(
    const float* __restrict__ in, u16* __restrict__ out, int R, int C) {
  __shared__ float tile[32][33];
  const int tx = threadIdx.x & 31, ty = threadIdx.x >> 5;   // 32 x 8
  const int c0 = blockIdx.x * 32, r0 = blockIdx.y * 32;
  for (int j = ty; j < 32; j += 8)
    tile[j][tx] = in[(size_t)(r0 + j) * C + c0 + tx];
  __syncthreads();
  for (int j = ty; j < 32; j += 8)
    out[(size_t)(c0 + j) * R + r0 + tx] = f2b(tile[tx][j]);
}

// ---------------- causal softmax over row, write bf16 probs -------------
// T <= 2048: each of 256 threads caches up to 8 row elements in registers
// (statically indexed) -> single global read pass instead of three.
__global__ __launch_bounds__(256) void k_softmax(
    const float* __restrict__ scores, u16* __restrict__ probs, int T) {
  const int r = blockIdx.x;        // r = b*T + i ; row data at scores + r*T
  const int i = r % T;
  const float* srow = scores + (size_t)r * T;
  u16* prow = probs + (size_t)r * T;
  const int t = threadIdx.x;
  const int n = i + 1;             // valid prefix length
  __shared__ float red[256];

  float vals[8];
#pragma unroll
  for (int c = 0; c < 8; c++) {
    const int j = t + c * 256;
    vals[c] = (j < n) ? srow[j] : -3.0e38f;
  }
  float mx = -3.0e38f;
#pragma unroll
  for (int c = 0; c < 8; c++) mx = fmaxf(mx, vals[c]);
  red[t] = mx; __syncthreads();
  for (int s = 128; s > 0; s >>= 1) {
    if (t < s) red[t] = fmaxf(red[t], red[t + s]);
    __syncthreads();
  }
  mx = red[0]; __syncthreads();
  float sum = 0.f;
#pragma unroll
  for (int c = 0; c < 8; c++) {
    const float e = (t + c * 256 < n) ? __expf(vals[c] - mx) : 0.0f;
    vals[c] = e; sum += e;
  }
  red[t] = sum; __syncthreads();
  for (int s = 128; s > 0; s >>= 1) {
    if (t < s) red[t] += red[t + s];
    __syncthreads();
  }
  const float inv = 1.0f / red[0];
#pragma unroll
  for (int c = 0; c < 8; c++) {
    const int j = t + c * 256;
    if (j < T) prow[j] = f2b(vals[c] * inv);
  }
}

// ---------------- NT GEMM: C = epilogue(alpha * A @ B^T + bias + src) ---
// A: [M,K] bf16 row-major. B: [N,K] bf16 row-major. M,N % 128 == 0,
// K % 32 == 0. Block = 256 thr = 4 waves, 128x128 tile, wave = 64x64 via
// 4x4 grid of mfma_f32_16x16x32_bf16. act: 0=none, 1=exact gelu.
// m97 structure: linear LDS [128][32] (64B rows, NO padding — required by
// global_load_lds's wave-uniform-base + lane*16B write pattern) staged via
// width-16 global_load_lds DMA (no VGPR round-trip, no VALU addr burn).
__global__ __launch_bounds__(256) void k_gemm_nt(
    const u16* __restrict__ A, const u16* __restrict__ B,
    const float* __restrict__ src, const float* __restrict__ bias,
    float* __restrict__ Cf, u16* __restrict__ Cb,
    int M, int N, int K, float alpha, int act, int causal_skip) {
  __shared__ __align__(16) u16 As[128 * 32];
  __shared__ __align__(16) u16 Bs[128 * 32];
  const int t = threadIdx.x;

  // XCD-aware block swizzle: contiguous grid chunk per XCD for L2 reuse of
  // shared B panels. Bijective iff nwg % 8 == 0 (true for every launch here;
  // guarded anyway).
  int bx = blockIdx.x, by = blockIdx.y;
  const int nwg = gridDim.x * gridDim.y;
  if ((nwg & 7) == 0) {
    int bid = by * gridDim.x + bx;
    bid = (bid & 7) * (nwg >> 3) + (bid >> 3);
    bx = bid % gridDim.x;
    by = bid / gridDim.x;
  }
  const int m0 = by * 128, n0 = bx * 128;
  if (causal_skip && n0 > m0 + 127) return;   // fully-masked score block

  const int lane = t & 63, wave = t >> 6;
  const int wm = (wave >> 1) * 64, wn = (wave & 1) * 64;
  const int lm = lane & 15, lq = lane >> 4;

  v4f acc[4][4];
#pragma unroll
  for (int i = 0; i < 4; i++)
#pragma unroll
    for (int j = 0; j < 4; j++)
#pragma unroll
      for (int r = 0; r < 4; r++) acc[i][j][r] = 0.0f;

  // DMA staging: wave w stages rows [w*32, w*32+32) of each tile as two
  // 1024B issues of 16 rows. Lane l sources row base+ (l>>2), 16B at bf16
  // col (l&3)*8; HW writes LDS at wave-uniform base + l*16 — matches the
  // linear [row][32] layout exactly.
  const int srow = lane >> 2;
  const int scol = (lane & 3) * 8;
  const u16* ag = A + (size_t)(m0 + wave * 32 + srow) * K + scol;
  const u16* bg = B + (size_t)(n0 + wave * 32 + srow) * K + scol;
  const size_t rstep = (size_t)16 * K;
  u16* const la0 = &As[(wave * 32) * 32];
  u16* const la1 = &As[(wave * 32 + 16) * 32];
  u16* const lb0 = &Bs[(wave * 32) * 32];
  u16* const lb1 = &Bs[(wave * 32 + 16) * 32];

  for (int k0 = 0; k0 < K; k0 += 32) {
    __builtin_amdgcn_global_load_lds(GLP(ag),         LDP(la0), 16, 0, 0);
    __builtin_amdgcn_global_load_lds(GLP(ag + rstep), LDP(la1), 16, 0, 0);
    __builtin_amdgcn_global_load_lds(GLP(bg),         LDP(lb0), 16, 0, 0);
    __builtin_amdgcn_global_load_lds(GLP(bg + rstep), LDP(lb1), 16, 0, 0);
    ag += 32; bg += 32;
    __syncthreads();   // compiler drains vmcnt(0) before s_barrier

    v8bf af[4], bfr[4];
#pragma unroll
    for (int i = 0; i < 4; i++)
      af[i] = *(const v8bf*)&As[(wm + i * 16 + lm) * 32 + lq * 8];
#pragma unroll
    for (int j = 0; j < 4; j++)
      bfr[j] = *(const v8bf*)&Bs[(wn + j * 16 + lm) * 32 + lq * 8];
#pragma unroll
    for (int i = 0; i < 4; i++)
#pragma unroll
      for (int j = 0; j < 4; j++)
        acc[i][j] = __builtin_amdgcn_mfma_f32_16x16x32_bf16(af[i], bfr[j], acc[i][j], 0, 0, 0);
    __syncthreads();
  }

  // epilogue: D layout col = lane&15, row = (lane>>4)*4 + reg
#pragma unroll
  for (int i = 0; i < 4; i++) {
#pragma unroll
    for (int j = 0; j < 4; j++) {
      const int col = n0 + wn + j * 16 + lm;
      const float bv = bias ? bias[col] : 0.0f;
      const int rowb = m0 + wm + i * 16 + lq * 4;
#pragma unroll
      for (int r = 0; r < 4; r++) {
        float v = alpha * acc[i][j][r] + bv;
        const size_t off = (size_t)(rowb + r) * N + col;
        if (src) v += src[off];
        if (act) v = 0.5f * v * (1.0f + erff(v * 0.70710678118654752f));
        if (Cf) Cf[off] = v;
        if (Cb) Cb[off] = f2b(v);
      }
    }
  }
}

extern "C" void kernel_launch(void* const* d_in, const int* in_sizes, int n_in,
                              void* d_out, int out_size, void* d_ws, size_t ws_size,
                              hipStream_t stream) {
  (void)in_sizes; (void)n_in; (void)out_size; (void)ws_size;
  const int B = 2, T = 2048, D = 1024, V = 32000, H = 4096, M = B * T;
  const int* idx   = (const int*)d_in[0];
  const float* tok = (const float*)d_in[1];
  const float* pos = (const float*)d_in[2];
  const float* Wq  = (const float*)d_in[3];
  const float* Wk  = (const float*)d_in[4];
  const float* Wv  = (const float*)d_in[5];
  const float* W1  = (const float*)d_in[6];
  const float* b1  = (const float*)d_in[7];
  const float* W2  = (const float*)d_in[8];
  const float* b2  = (const float*)d_in[9];
  const float* Wout = (const float*)d_in[10];
  const float* bout = (const float*)d_in[11];
  float* out = (float*)d_out;

  // workspace layout (192 MB total, with reuse)
  char* w = (char*)d_ws;
  const size_t MB = 1u << 20;
  float* x      = (float*)(w);             // 16 MB  [M,D] f32
  u16*  xb      = (u16*)(w + 16 * MB);     //  8 MB  [M,D] bf16
  u16*  qb      = (u16*)(w + 24 * MB);     //  8 MB
  u16*  kb      = (u16*)(w + 32 * MB);     //  8 MB
  u16*  vt      = (u16*)(w + 40 * MB);     //  8 MB  per-batch [D,T] bf16
  float* vf     = (float*)(w + 48 * MB);   // 16 MB  v f32; dead after vt -> reuse as x2
  float* x2     = vf;
  float* scores = (float*)(w + 64 * MB);   // 32 MB  [B,T,T] f32; dead after softmax -> hb
  u16*  hb      = (u16*)(w + 64 * MB);     // 32 MB  [M,H] bf16
  u16*  probs   = (u16*)(w + 96 * MB);     // 16 MB  [B,T,T] bf16
  u16*  x2b     = (u16*)(w + 112 * MB);    //  8 MB
  u16*  x3b     = (u16*)(w + 120 * MB);    //  8 MB
  u16*  wT      = (u16*)(w + 128 * MB);    // 64 MB  transposed weight scratch (max: Wout)

  dim3 blk(256);

  // 1. embed
  k_embed<<<M, blk, 0, stream>>>(idx, tok, pos, x, xb, T, D);

  // 2-4. q, k, v projections (weights transposed+cast into wT sequentially)
  k_castT<<<dim3(D / 32, D / 32), blk, 0, stream>>>(Wq, wT, D, D);
  k_gemm_nt<<<dim3(D / 128, M / 128), blk, 0, stream>>>(
      xb, wT, nullptr, nullptr, nullptr, qb, M, D, D, 1.0f, 0, 0);
  k_castT<<<dim3(D / 32, D / 32), blk, 0, stream>>>(Wk, wT, D, D);
  k_gemm_nt<<<dim3(D / 128, M / 128), blk, 0, stream>>>(
      xb, wT, nullptr, nullptr, nullptr, kb, M, D, D, 1.0f, 0, 0);
  k_castT<<<dim3(D / 32, D / 32), blk, 0, stream>>>(Wv, wT, D, D);
  k_gemm_nt<<<dim3(D / 128, M / 128), blk, 0, stream>>>(
      xb, wT, nullptr, nullptr, vf, nullptr, M, D, D, 1.0f, 0, 0);

  // 5. v^T per batch: [T,D] f32 -> [D,T] bf16
  for (int b = 0; b < B; b++)
    k_castT<<<dim3(D / 32, T / 32), blk, 0, stream>>>(
        vf + (size_t)b * T * D, vt + (size_t)b * D * T, T, D);

  // 6. scores = q k^T / sqrt(D) per batch (skip fully-masked blocks)
  for (int b = 0; b < B; b++)
    k_gemm_nt<<<dim3(T / 128, T / 128), blk, 0, stream>>>(
        qb + (size_t)b * T * D, kb + (size_t)b * T * D, nullptr, nullptr,
        scores + (size_t)b * T * T, nullptr, T, T, D, 1.0f / 32.0f, 0, 1);

  // 7. causal softmax -> bf16 probs (zeros past diagonal)
  k_softmax<<<B * T, blk, 0, stream>>>(scores, probs, T);

  // 8. x2 = x + 0.125 * probs @ v   (B operand = v^T)
  for (int b = 0; b < B; b++)
    k_gemm_nt<<<dim3(D / 128, T / 128), blk, 0, stream>>>(
        probs + (size_t)b * T * T, vt + (size_t)b * D * T,
        x + (size_t)b * T * D, nullptr,
        x2 + (size_t)b * T * D, x2b + (size_t)b * T * D, T, D, T, 0.125f, 0, 0);

  // 9. h = gelu(x2 @ W1 + b1) -> bf16 only
  k_castT<<<dim3(H / 32, D / 32), blk, 0, stream>>>(W1, wT, D, H);
  k_gemm_nt<<<dim3(H / 128, M / 128), blk, 0, stream>>>(
      x2b, wT, nullptr, b1, nullptr, hb, M, H, D, 1.0f, 1, 0);

  // 10. x3 = x2 + h @ W2 + b2 -> bf16 only
  k_castT<<<dim3(D / 32, H / 32), blk, 0, stream>>>(W2, wT, H, D);
  k_gemm_nt<<<dim3(D / 128, M / 128), blk, 0, stream>>>(
      hb, wT, x2, b2, nullptr, x3b, M, D, H, 1.0f, 0, 0);

  // 11. out = x3 @ Wout + bout (f32)
  k_castT<<<dim3(V / 32, D / 32), blk, 0, stream>>>(Wout, wT, D, V);
  k_gemm_nt<<<dim3(V / 128, M / 128), blk, 0, stream>>>(
      x3b, wT, nullptr, bout, out, nullptr, M, V, D, 1.0f, 0, 0);
}